// Round 1
// 1593.702 us; speedup vs baseline: 1.3286x; 1.3286x over previous
//
#include <hip/hip_runtime.h>
#include <stdint.h>

// ---------------------------------------------------------------------------
// QuantizedLinear: out = inp @ (q_w * scale_w[:,None]).T + bias
//   inp[M,K] fp32, quant_w[N,K] int32 (int8 range), scale_w[N], bias[N]
// GEMM on unscaled bf16 weights (int8 exact in bf16), fp32 scale+bias epilogue.
//
// GEMM structure: 256x256 tile, BK=64, 8 waves (2x4), 4-phase/K-tile schedule
// with counted vmcnt (never 0 in main loop), st-16B XOR LDS swizzle
// (linear gld_lds dest + inverse-swizzled source + swizzled ds_read),
// setprio around MFMA clusters, bijective XCD blockIdx swizzle.
// ---------------------------------------------------------------------------

typedef unsigned short u16;
using frag_t = __attribute__((ext_vector_type(8))) short;   // 8 bf16
using f32x4  = __attribute__((ext_vector_type(4))) float;   // MFMA C/D
using u16x8  = __attribute__((ext_vector_type(8))) u16;

#define BM 256
#define BN 256
#define BK 64
#define HB 8192   // u16 elems per 128x64 half-buffer (16 KiB)

#define VMW(n) asm volatile("s_waitcnt vmcnt(" #n ")" ::: "memory")
#define BAR()  asm volatile("s_barrier" ::: "memory")

__device__ __forceinline__ void gld_lds16(const void* g, void* l) {
    __builtin_amdgcn_global_load_lds(
        (const __attribute__((address_space(1))) void*)g,
        (__attribute__((address_space(3))) void*)l,
        16, 0, 0);
}

// fp32 -> bf16 RTNE
__device__ __forceinline__ u16 f2bf(float f) {
    uint32_t u = __builtin_bit_cast(uint32_t, f);
    u += 0x7fffu + ((u >> 16) & 1u);
    return (u16)(u >> 16);
}

// ---- prepass 1: fp32 -> bf16, 8 elements/thread ---------------------------
__global__ void cvt_f32_to_bf16(const float* __restrict__ in,
                                u16* __restrict__ out, long n8) {
    long i = (long)blockIdx.x * blockDim.x + threadIdx.x;
    if (i >= n8) return;
    long base = i * 8;
    const float4* p = (const float4*)(in + base);
    float4 f0 = p[0], f1 = p[1];
    u16x8 o;
    o[0] = f2bf(f0.x); o[1] = f2bf(f0.y); o[2] = f2bf(f0.z); o[3] = f2bf(f0.w);
    o[4] = f2bf(f1.x); o[5] = f2bf(f1.y); o[6] = f2bf(f1.z); o[7] = f2bf(f1.w);
    *(u16x8*)(out + base) = o;
}

// ---- prepass 2: int32 -> bf16 (exact for |v| <= 255) ----------------------
__global__ void cvt_i32_to_bf16(const int* __restrict__ in,
                                u16* __restrict__ out, long n8) {
    long i = (long)blockIdx.x * blockDim.x + threadIdx.x;
    if (i >= n8) return;
    long base = i * 8;
    const int4* p = (const int4*)(in + base);
    int4 a = p[0], b = p[1];
    u16x8 o;
    o[0] = f2bf((float)a.x); o[1] = f2bf((float)a.y);
    o[2] = f2bf((float)a.z); o[3] = f2bf((float)a.w);
    o[4] = f2bf((float)b.x); o[5] = f2bf((float)b.y);
    o[6] = f2bf((float)b.z); o[7] = f2bf((float)b.w);
    *(u16x8*)(out + base) = o;
}

// ---------------------------------------------------------------------------
// Main GEMM. A[M,K] bf16 row-major, B[N,K] bf16 row-major (B^T input).
// 512 threads = 8 waves in 2(M) x 4(N); each wave owns a 128x64 output tile
// (8x4 fragments of 16x16), acc = f32x4[8][4].
//
// K-tile T (BK=64) is staged as 4 half-tiles: s0=Ah0, s1=Bh0, s2=Bh1, s3=Ah1,
// where Ah_qm = A tile rows with (row>>6)&1==qm  (local row = wm*64+(g&63)),
//       Bh_qn = B tile rows with (row>>5)&1==qn  (local row = wn*32+(g&31)).
// Half-tile sequence h = 4T+s; stage at phase P stages h = P+6 (lead 6).
// Phases of tile T compute C-quadrants (qm,qn) in order (0,0)(0,1)(1,1)(1,0);
// B frags are read once (p0: qn0, p1: qn1) and carried in regs all tile, so
// every LDS region's last read is >=2 phases before its restage (race-free).
// vmcnt(8) at p0/p1/p2 lands exactly h_req = 4T+1 / 4T+2 / 4T+3; p3 waits
// nothing. Last tile drains 4 -> 2 -> 0.
//
// LDS swizzle: 16B slot s' = s ^ (row&7) -> every 8-lane group of a
// ds_read_b128 covers all 32 banks. gld_lds dest stays linear; the source
// column is pre-swizzled (rule: both-sides-or-neither).
// ---------------------------------------------------------------------------
__global__ __launch_bounds__(512, 2)
void gemm256(const u16* __restrict__ A, const u16* __restrict__ B,
             const float* __restrict__ scale, const float* __restrict__ bias,
             float* __restrict__ C, int M, int N, int K) {
    extern __shared__ u16 lds[];
    u16* As = lds;             // [buf][qm][128*64]
    u16* Bs = lds + 4 * HB;    // [buf][qn][128*64]

    const int tid  = threadIdx.x;
    const int wv   = tid >> 6;
    const int lane = tid & 63;
    const int wm   = wv >> 2;        // 0..1
    const int wn   = wv & 3;         // 0..3

    // bijective XCD swizzle (nwg % 8 == 0 here: 32*64 = 2048)
    const int nbx = N / BN;
    const int nwg = (M / BM) * nbx;
    const int cpx = nwg >> 3;
    const int gid = blockIdx.x;
    const int wg  = (gid & 7) * cpx + (gid >> 3);
    const long row0 = (long)(wg / nbx) * BM;
    const long col0 = (long)(wg % nbx) * BN;
    const int NT = K / BK;

    // ---- staging map: round l covers LDS bytes [(wv*2+l)*1024, +1024) of a
    // half-buffer; local row r = (wv*2+l)*8 + (lane>>3), slot s' = lane&7;
    // source column element = ((s' ^ (r&7)) * 8)  [inverse swizzle]
    const int r0 = (wv * 2 + 0) * 8 + (lane >> 3);
    const int r1 = (wv * 2 + 1) * 8 + (lane >> 3);
    const int sl = lane & 7;
    const u16* a0 = A + (row0 + ((r0 >> 6) * 128 + (r0 & 63))) * (long)K + ((sl ^ (r0 & 7)) << 3);
    const u16* a1 = A + (row0 + ((r1 >> 6) * 128 + (r1 & 63))) * (long)K + ((sl ^ (r1 & 7)) << 3);
    const u16* b0 = B + (col0 + ((r0 >> 5) * 64 + (r0 & 31))) * (long)K + ((sl ^ (r0 & 7)) << 3);
    const u16* b1 = B + (col0 + ((r1 >> 5) * 64 + (r1 & 31))) * (long)K + ((sl ^ (r1 & 7)) << 3);
    const int d0 = (wv * 2 + 0) * 512;   // u16 elems, wave-uniform LDS dest
    const int d1 = (wv * 2 + 1) * 512;

    // ---- fragment read offsets (swizzled): frag elem k = kk*32+(lane>>4)*8+j
    const int frow = lane & 15;
    const int kgrp = lane >> 4;
    const int oe0  = frow * 64 + (((kgrp    ) ^ (frow & 7)) << 3);
    const int oe1  = frow * 64 + (((kgrp + 4) ^ (frow & 7)) << 3);

    f32x4  acc[8][4] = {};
    frag_t af[4][2];       // A quadrant frags [i][kk]  (reloaded at p0/p2)
    frag_t bf[2][2][2];    // B frags [qn][j][kk]       (carried all tile)

#define STAGE_A(th, qm, bufq) do {                                   \
    u16* dst = As + ((bufq) * 2 + (qm)) * HB;                        \
    const long ko = (long)(th) * BK + (long)(qm) * 64 * K;           \
    gld_lds16(a0 + ko, dst + d0);                                    \
    gld_lds16(a1 + ko, dst + d1); } while (0)

#define STAGE_B(th, qn, bufq) do {                                   \
    u16* dst = Bs + ((bufq) * 2 + (qn)) * HB;                        \
    const long ko = (long)(th) * BK + (long)(qn) * 32 * K;           \
    gld_lds16(b0 + ko, dst + d0);                                    \
    gld_lds16(b1 + ko, dst + d1); } while (0)

#define LOAD_A(qm, bufq) do {                                        \
    const u16* p = As + ((bufq) * 2 + (qm)) * HB + wm * 64 * 64;     \
    _Pragma("unroll") for (int i = 0; i < 4; ++i) {                  \
        af[i][0] = *(const frag_t*)(p + i * 16 * 64 + oe0);          \
        af[i][1] = *(const frag_t*)(p + i * 16 * 64 + oe1); } } while (0)

#define LOAD_B(qn, bufq) do {                                        \
    const u16* p = Bs + ((bufq) * 2 + (qn)) * HB + wn * 32 * 64;     \
    _Pragma("unroll") for (int j = 0; j < 2; ++j) {                  \
        bf[qn][j][0] = *(const frag_t*)(p + j * 16 * 64 + oe0);      \
        bf[qn][j][1] = *(const frag_t*)(p + j * 16 * 64 + oe1); } } while (0)

#define MFMA_Q(qm, qn) do {                                          \
    __builtin_amdgcn_s_setprio(1);                                   \
    _Pragma("unroll") for (int i = 0; i < 4; ++i)                    \
    _Pragma("unroll") for (int j = 0; j < 2; ++j) {                  \
        acc[(qm)*4+i][(qn)*2+j] = __builtin_amdgcn_mfma_f32_16x16x32_bf16( \
            af[i][0], bf[qn][j][0], acc[(qm)*4+i][(qn)*2+j], 0, 0, 0);     \
        acc[(qm)*4+i][(qn)*2+j] = __builtin_amdgcn_mfma_f32_16x16x32_bf16( \
            af[i][1], bf[qn][j][1], acc[(qm)*4+i][(qn)*2+j], 0, 0, 0); }   \
    __builtin_amdgcn_s_setprio(0); } while (0)

    // prologue: stage h = 0..5  (tile0 complete, tile1 Ah0+Bh0)
    STAGE_A(0, 0, 0); STAGE_B(0, 0, 0); STAGE_B(0, 1, 0); STAGE_A(0, 1, 0);
    STAGE_A(1, 0, 1); STAGE_B(1, 0, 1);

    int T = 0;
    for (; T < NT - 2; ++T) {
        const int buf = T & 1;
        // p0: needs h<=4T+1 landed (Ah0,Bh0 of T)
        VMW(8); BAR();
        LOAD_A(0, buf); LOAD_B(0, buf);
        STAGE_B(T + 1, 1, buf ^ 1);          // h = 4T+6
        MFMA_Q(0, 0);
        // p1: needs h<=4T+2 (Bh1 of T)
        VMW(8); BAR();
        LOAD_B(1, buf);
        STAGE_A(T + 1, 1, buf ^ 1);          // h = 4T+7
        MFMA_Q(0, 1);
        // p2: needs h<=4T+3 (Ah1 of T)
        VMW(8); BAR();
        LOAD_A(1, buf);
        STAGE_A(T + 2, 0, buf);              // h = 4T+8 (region dead since p0)
        MFMA_Q(1, 1);
        // p3: register-only compute; stage into region dead since p0
        STAGE_B(T + 2, 0, buf);              // h = 4T+9
        MFMA_Q(1, 0);
    }
    {   // T = NT-2: last two stages already out of range
        const int buf = T & 1;
        VMW(8); BAR();
        LOAD_A(0, buf); LOAD_B(0, buf);
        STAGE_B(T + 1, 1, buf ^ 1);          // h = 4NT-2
        MFMA_Q(0, 0);
        VMW(8); BAR();
        LOAD_B(1, buf);
        STAGE_A(T + 1, 1, buf ^ 1);          // h = 4NT-1
        MFMA_Q(0, 1);
        VMW(8); BAR();
        LOAD_A(1, buf);
        MFMA_Q(1, 1);
        MFMA_Q(1, 0);
        ++T;
    }
    {   // T = NT-1: epilogue drain 4 -> 2 -> 0
        const int buf = T & 1;
        VMW(4); BAR();
        LOAD_A(0, buf); LOAD_B(0, buf);
        MFMA_Q(0, 0);
        VMW(2); BAR();
        LOAD_B(1, buf);
        MFMA_Q(0, 1);
        VMW(0); BAR();
        LOAD_A(1, buf);
        MFMA_Q(1, 1);
        MFMA_Q(1, 0);
    }

    // epilogue: C/D layout col = lane&15, row = (lane>>4)*4 + reg  [m89/m91]
    const int crow = (lane >> 4) * 4;
    const int ccol = lane & 15;
    const long orow = row0 + wm * 128;
    const long ocol = col0 + wn * 64 + ccol;
    float sc[4], bi[4];
#pragma unroll
    for (int j = 0; j < 4; ++j) {
        sc[j] = scale[ocol + j * 16];
        bi[j] = bias[ocol + j * 16];
    }
#pragma unroll
    for (int i = 0; i < 8; ++i) {
#pragma unroll
        for (int r = 0; r < 4; ++r) {
            float* cp = C + (orow + i * 16 + crow + r) * (long)N + ocol;
#pragma unroll
            for (int j = 0; j < 4; ++j)
                cp[j * 16] = acc[i][j][r] * sc[j] + bi[j];
        }
    }
#undef STAGE_A
#undef STAGE_B
#undef LOAD_A
#undef LOAD_B
#undef MFMA_Q
}

extern "C" void kernel_launch(void* const* d_in, const int* in_sizes, int n_in,
                              void* d_out, int out_size, void* d_ws, size_t ws_size,
                              hipStream_t stream) {
    const float* inp   = (const float*)d_in[0];
    const int*   qw    = (const int*)d_in[1];
    const float* scale = (const float*)d_in[2];
    const float* bias  = (const float*)d_in[3];

    const long n_inp = (long)in_sizes[0];      // M*K
    const long n_w   = (long)in_sizes[1];      // N*K
    const int  N     = in_sizes[2];
    const int  K     = (int)(n_w / N);
    const int  M     = (int)(n_inp / K);

    u16* a_bf = (u16*)d_ws;              // M*K bf16
    u16* b_bf = (u16*)d_ws + n_inp;      // N*K bf16

    {
        long n8 = n_inp / 8;
        cvt_f32_to_bf16<<<(int)((n8 + 255) / 256), 256, 0, stream>>>(inp, a_bf, n8);
    }
    {
        long n8 = n_w / 8;
        cvt_i32_to_bf16<<<(int)((n8 + 255) / 256), 256, 0, stream>>>(qw, b_bf, n8);
    }

    static int attr_set = 0;
    if (!attr_set) {
        hipFuncSetAttribute((const void*)gemm256,
                            hipFuncAttributeMaxDynamicSharedMemorySize, 131072);
        attr_set = 1;
    }
    const int nwg = (M / BM) * (N / BN);   // 32 * 64 = 2048
    gemm256<<<nwg, 512, 131072, stream>>>(a_bf, b_bf, scale, bias,
                                          (float*)d_out, M, N, K);
}